// Round 4
// baseline (456.210 us; speedup 1.0000x reference)
//
#include <hip/hip_runtime.h>

#define BINS 10
#define GRID 2048
#define BLOCK 256
#define NWAVES (BLOCK / 64)

// native clang vector type: __builtin_nontemporal_load accepts this
// (HIP's float4 is a struct and is rejected — R3 compile failure).
typedef float vfloat4 __attribute__((ext_vector_type(4)));

// Thread-per-row (C=16, 4 float4 loads/row). Histogram lives entirely in
// REGISTERS (10 f32 + 10 u32 per thread, predicated adds) -> zero LDS traffic
// and zero loop-carried memory dependence in the hot loop. Softmax via
// s = sum(exp(x_i - x_t)): no max pass needed (inputs ~N(0,1), exponents
// bounded), nll = log(s), p_t = 1/s. __expf/__logf = HW transcendentals.
__global__ __launch_bounds__(BLOCK) void ghm_main(const float* __restrict__ x,
                                                  const int* __restrict__ tgt,
                                                  float* __restrict__ p_sum,
                                                  unsigned int* __restrict__ p_cnt,
                                                  int n_rows) {
    float h_sum[BINS];
    unsigned int h_cnt[BINS];
    #pragma unroll
    for (int b = 0; b < BINS; ++b) { h_sum[b] = 0.0f; h_cnt[b] = 0u; }

    const int gid = blockIdx.x * BLOCK + threadIdx.x;
    const int stride = GRID * BLOCK;
    const vfloat4* __restrict__ xv = (const vfloat4*)x;

    const float edges[BINS] = {0.1f, 0.2f, 0.3f, 0.4f, 0.5f,
                               0.6f, 0.7f, 0.8f, 0.9f, 1.0f};

    for (int r = gid; r < n_rows; r += stride) {
        const vfloat4 v0 = __builtin_nontemporal_load(&xv[(size_t)r * 4 + 0]);
        const vfloat4 v1 = __builtin_nontemporal_load(&xv[(size_t)r * 4 + 1]);
        const vfloat4 v2 = __builtin_nontemporal_load(&xv[(size_t)r * 4 + 2]);
        const vfloat4 v3 = __builtin_nontemporal_load(&xv[(size_t)r * 4 + 3]);
        const int tg = tgt[r];

        // x_target (generic over class 0..15; setup uses 0/1)
        const vfloat4 vs = (tg < 8) ? ((tg < 4) ? v0 : v1) : ((tg < 12) ? v2 : v3);
        const int c = tg & 3;
        const float xt = (c < 2) ? ((c == 0) ? vs.x : vs.y) : ((c == 2) ? vs.z : vs.w);

        const float s =
            __expf(v0.x - xt) + __expf(v0.y - xt) + __expf(v0.z - xt) + __expf(v0.w - xt) +
            __expf(v1.x - xt) + __expf(v1.y - xt) + __expf(v1.z - xt) + __expf(v1.w - xt) +
            __expf(v2.x - xt) + __expf(v2.y - xt) + __expf(v2.z - xt) + __expf(v2.w - xt) +
            __expf(v3.x - xt) + __expf(v3.y - xt) + __expf(v3.z - xt) + __expf(v3.w - xt);

        const float nll = __logf(s);          // -log p_t
        const float p = 1.0f / s;             // p_t
        const float g = fabsf(p - (float)tg); // gradient norm

        int b = 0;
        #pragma unroll
        for (int k = 0; k < BINS; ++k) b += (g >= edges[k]) ? 1 : 0;
        b = (b > BINS - 1) ? (BINS - 1) : b;

        #pragma unroll
        for (int k = 0; k < BINS; ++k) {
            if (b == k) { h_sum[k] += nll; h_cnt[k] += 1u; }  // predicated, stays in regs
        }
    }

    // wave shuffle-reduce, then tiny LDS fold across the block's 4 waves
    __shared__ float ls[NWAVES * BINS];
    __shared__ unsigned int lc[NWAVES * BINS];
    const int lane = threadIdx.x & 63;
    const int wv = threadIdx.x >> 6;
    #pragma unroll
    for (int b = 0; b < BINS; ++b) {
        float s = h_sum[b];
        unsigned int cn = h_cnt[b];
        #pragma unroll
        for (int off = 32; off > 0; off >>= 1) {
            s += __shfl_xor(s, off);
            cn += __shfl_xor(cn, off);
        }
        if (lane == 0) { ls[wv * BINS + b] = s; lc[wv * BINS + b] = cn; }
    }
    __syncthreads();

    if (threadIdx.x < BINS) {
        float s = 0.0f;
        unsigned int cn = 0u;
        #pragma unroll
        for (int w = 0; w < NWAVES; ++w) { s += ls[w * BINS + threadIdx.x]; cn += lc[w * BINS + threadIdx.x]; }
        p_sum[threadIdx.x * GRID + blockIdx.x] = s;
        p_cnt[threadIdx.x * GRID + blockIdx.x] = cn;
    }
}

__global__ void ghm_final(const float* __restrict__ p_sum,
                          const unsigned int* __restrict__ p_cnt,
                          float* __restrict__ out, int n_rows) {
    const int lane = threadIdx.x;  // 64 threads, 1 wave
    double total = 0.0;
    for (int b = 0; b < BINS; ++b) {
        double s = 0.0;
        unsigned long long c = 0;
        for (int k = lane; k < GRID; k += 64) {
            s += (double)p_sum[b * GRID + k];
            c += (unsigned long long)p_cnt[b * GRID + k];
        }
        #pragma unroll
        for (int off = 32; off > 0; off >>= 1) {
            s += __shfl_xor(s, off);
            c += __shfl_xor(c, off);
        }
        double cd = (double)c;
        if (cd < 1.0) cd = 1.0;
        total += s / cd;
    }
    if (lane == 0) out[0] = (float)(total * ((double)n_rows / (double)BINS));
}

extern "C" void kernel_launch(void* const* d_in, const int* in_sizes, int n_in,
                              void* d_out, int out_size, void* d_ws, size_t ws_size,
                              hipStream_t stream) {
    const float* x = (const float*)d_in[0];
    const int* tgt = (const int*)d_in[1];
    const int n_rows = in_sizes[1];  // N = 4194304

    float* p_sum = (float*)d_ws;                                       // [BINS][GRID]
    unsigned int* p_cnt = (unsigned int*)((char*)d_ws + BINS * GRID * sizeof(float));

    ghm_main<<<GRID, BLOCK, 0, stream>>>(x, tgt, p_sum, p_cnt, n_rows);
    ghm_final<<<1, 64, 0, stream>>>(p_sum, p_cnt, (float*)d_out, n_rows);
}

// Round 5
// 452.785 us; speedup vs baseline: 1.0076x; 1.0076x over previous
//
#include <hip/hip_runtime.h>

#define BINS 10
#define GRID 2048
#define BLOCK 256
#define NWAVES (BLOCK / 64)

// Quad-per-row layout (R1's): 4 lanes per row, lane j loads float4 #j of the
// row -> every global_load_dwordx4 is 64 lanes x 16 B CONTIGUOUS (1 KiB/instr,
// fully coalesced). R2/R4's thread-per-row had 64-B lane stride = 64 cache
// lines per instruction (request-rate bound) and regressed.
// Histogram: per-thread REGISTERS (R4's), no atomics, no LDS in hot loop.
// Softmax without max-pass: s = sum(exp(x_i - x_t)), nll = log s, p = 1/s.
// x_t broadcast across the quad via one __shfl.
__global__ __launch_bounds__(BLOCK) void ghm_main(const float* __restrict__ x,
                                                  const int* __restrict__ tgt,
                                                  float* __restrict__ p_sum,
                                                  unsigned int* __restrict__ p_cnt,
                                                  int n_rows) {
    float h_sum[BINS];
    unsigned int h_cnt[BINS];
    #pragma unroll
    for (int b = 0; b < BINS; ++b) { h_sum[b] = 0.0f; h_cnt[b] = 0u; }

    const int lane = threadIdx.x & 63;
    const int j = threadIdx.x & 3;                                  // lane-in-quad
    const int quad0 = (blockIdx.x * BLOCK + threadIdx.x) >> 2;      // starting row
    const int quads_total = (GRID * BLOCK) >> 2;
    const float4* __restrict__ xv = (const float4*)x;

    const float edges[BINS] = {0.1f, 0.2f, 0.3f, 0.4f, 0.5f,
                               0.6f, 0.7f, 0.8f, 0.9f, 1.0f};

    for (int r = quad0; r < n_rows; r += quads_total) {
        const float4 v = xv[(size_t)r * 4 + j];   // contiguous 1 KiB per wave
        const int tg = tgt[r];                    // quad-uniform (4-way broadcast)

        // candidate x_target from this lane's 4 classes; broadcast from the
        // quad lane that owns class tg (lane quadbase + tg/4).
        const int c = tg & 3;
        const float cand = (c < 2) ? ((c == 0) ? v.x : v.y) : ((c == 2) ? v.z : v.w);
        const float xt = __shfl(cand, (lane & 60) + (tg >> 2));

        // quad partial sum of exp(x_i - x_t), then butterfly within quad
        float s = __expf(v.x - xt) + __expf(v.y - xt) + __expf(v.z - xt) + __expf(v.w - xt);
        s += __shfl_xor(s, 1);
        s += __shfl_xor(s, 2);

        if (j == 0) {
            const float nll = __logf(s);           // -log p_t
            const float g = fabsf(1.0f / s - (float)tg);

            int b = 0;
            #pragma unroll
            for (int k = 0; k < BINS; ++k) b += (g >= edges[k]) ? 1 : 0;
            b = (b > BINS - 1) ? (BINS - 1) : b;

            #pragma unroll
            for (int k = 0; k < BINS; ++k) {
                if (b == k) { h_sum[k] += nll; h_cnt[k] += 1u; }   // stays in regs
            }
        }
    }

    // wave shuffle-reduce, then tiny LDS fold across the block's 4 waves
    __shared__ float ls[NWAVES * BINS];
    __shared__ unsigned int lc[NWAVES * BINS];
    const int wv = threadIdx.x >> 6;
    #pragma unroll
    for (int b = 0; b < BINS; ++b) {
        float s = h_sum[b];
        unsigned int cn = h_cnt[b];
        #pragma unroll
        for (int off = 32; off > 0; off >>= 1) {
            s += __shfl_xor(s, off);
            cn += __shfl_xor(cn, off);
        }
        if (lane == 0) { ls[wv * BINS + b] = s; lc[wv * BINS + b] = cn; }
    }
    __syncthreads();

    if (threadIdx.x < BINS) {
        float s = 0.0f;
        unsigned int cn = 0u;
        #pragma unroll
        for (int w = 0; w < NWAVES; ++w) { s += ls[w * BINS + threadIdx.x]; cn += lc[w * BINS + threadIdx.x]; }
        p_sum[threadIdx.x * GRID + blockIdx.x] = s;
        p_cnt[threadIdx.x * GRID + blockIdx.x] = cn;
    }
}

__global__ void ghm_final(const float* __restrict__ p_sum,
                          const unsigned int* __restrict__ p_cnt,
                          float* __restrict__ out, int n_rows) {
    const int lane = threadIdx.x;  // 64 threads, 1 wave
    double total = 0.0;
    for (int b = 0; b < BINS; ++b) {
        double s = 0.0;
        unsigned long long c = 0;
        for (int k = lane; k < GRID; k += 64) {
            s += (double)p_sum[b * GRID + k];
            c += (unsigned long long)p_cnt[b * GRID + k];
        }
        #pragma unroll
        for (int off = 32; off > 0; off >>= 1) {
            s += __shfl_xor(s, off);
            c += __shfl_xor(c, off);
        }
        double cd = (double)c;
        if (cd < 1.0) cd = 1.0;
        total += s / cd;
    }
    if (lane == 0) out[0] = (float)(total * ((double)n_rows / (double)BINS));
}

extern "C" void kernel_launch(void* const* d_in, const int* in_sizes, int n_in,
                              void* d_out, int out_size, void* d_ws, size_t ws_size,
                              hipStream_t stream) {
    const float* x = (const float*)d_in[0];
    const int* tgt = (const int*)d_in[1];
    const int n_rows = in_sizes[1];  // N = 4194304

    float* p_sum = (float*)d_ws;                                       // [BINS][GRID]
    unsigned int* p_cnt = (unsigned int*)((char*)d_ws + BINS * GRID * sizeof(float));

    ghm_main<<<GRID, BLOCK, 0, stream>>>(x, tgt, p_sum, p_cnt, n_rows);
    ghm_final<<<1, 64, 0, stream>>>(p_sum, p_cnt, (float*)d_out, n_rows);
}